// Round 1
// baseline (8024.591 us; speedup 1.0000x reference)
//
#include <hip/hip_runtime.h>

typedef _Float16 half_t;
typedef _Float16 half2_t __attribute__((ext_vector_type(2)));

constexpr int Msz = 128;
constexpr int MA  = 129;    // augmented size (with dustbin)
constexpr int PAD = 136;    // fp16 vector length padded to multiple of 8
constexpr int NB  = PAD / 8;  // 17 uint4 (b128) blocks
constexpr int NH  = PAD / 2;  // 68 half2 registers
constexpr int ITERS = 10000;

__device__ __forceinline__ float dot2(half2_t a, half2_t b, float acc) {
#if defined(__has_builtin)
#if __has_builtin(__builtin_amdgcn_fdot2)
    return __builtin_amdgcn_fdot2(a, b, acc, false);
#else
    return acc + (float)a[0] * (float)b[0] + (float)a[1] * (float)b[1];
#endif
#else
    return acc + (float)a[0] * (float)b[0] + (float)a[1] * (float)b[1];
#endif
}

__device__ __forceinline__ half2_t u2h(unsigned int u) {
    union { unsigned int u; half2_t h; } c; c.u = u; return c.h;
}

__global__ __launch_bounds__(192) void sinkhorn_k(
    const float* __restrict__ cost,
    const float* __restrict__ bin,
    float* __restrict__ out)
{
    const int b   = blockIdx.x;
    const int tid = threadIdx.x;

    __shared__ uint4 cb4[NB];   // c vector, fp16 packed
    __shared__ uint4 rb4[NB];   // r vector, fp16 packed
    __shared__ float vfin[MA];  // final v (fp32) for output

    half_t* ch = reinterpret_cast<half_t*>(cb4);
    half_t* rh = reinterpret_cast<half_t*>(rb4);

    const float alpha = bin[0];
    const float ea    = expf(alpha);
    const float* cm   = cost + (size_t)b * Msz * Msz;

    // init exchange buffers: c = 1 for real entries, 0 in the pad; r pad = 0
    if (tid < PAD) {
        ch[tid] = (tid < MA) ? (half_t)1.0f : (half_t)0.0f;
        rh[tid] = (half_t)0.0f;
    }

    // K row i (kr) and K^T row i (kt) resident in registers as fp16 pairs.
    // K = exp(Z0); Z0 = [[scores, a],[a, a]].
    half2_t kr[NH], kt[NH];
    if (tid < MA) {
        #pragma unroll
        for (int jj = 0; jj < NH; ++jj) {
            float f[2], g[2];
            #pragma unroll
            for (int e = 0; e < 2; ++e) {
                const int j = 2 * jj + e;
                float kv, ktv;
                if (j < Msz) {
                    kv  = (tid < Msz) ? expf(cm[tid * Msz + j]) : ea;
                    ktv = (tid < Msz) ? expf(cm[j * Msz + tid]) : ea;
                } else if (j == Msz) {
                    kv  = ea;
                    ktv = ea;
                } else {
                    kv  = 0.0f;
                    ktv = 0.0f;
                }
                f[e] = kv;
                g[e] = ktv;
            }
            half2_t h1; h1[0] = (half_t)f[0]; h1[1] = (half_t)f[1];
            half2_t h2; h2[0] = (half_t)g[0]; h2[1] = (half_t)g[1];
            kr[jj] = h1;
            kt[jj] = h2;
        }
    }
    __syncthreads();

    // Linear-domain Sinkhorn with mu,nu scaled by 256:
    //   muS = 1 (i<128) or 128 (dustbin);  r' = 256*r stays in fp16-friendly range.
    //   u = log(r') - log(256), v = log(c).
    float lastR = 1.0f, lastC = 1.0f;
    for (int it = 0; it < ITERS; ++it) {
        if (tid < MA) {
            float s0 = 0.f, s1 = 0.f, s2 = 0.f, s3 = 0.f;
            #pragma unroll
            for (int q = 0; q < NB; ++q) {
                uint4 cv = cb4[q];           // broadcast ds_read_b128
                s0 = dot2(kr[4*q+0], u2h(cv.x), s0);
                s1 = dot2(kr[4*q+1], u2h(cv.y), s1);
                s2 = dot2(kr[4*q+2], u2h(cv.z), s2);
                s3 = dot2(kr[4*q+3], u2h(cv.w), s3);
            }
            const float s   = (s0 + s1) + (s2 + s3);
            const float muS = (tid < Msz) ? 1.0f : 128.0f;
            lastR = muS / s;
            rh[tid] = (half_t)lastR;
        }
        __syncthreads();
        if (tid < MA) {
            float t0 = 0.f, t1 = 0.f, t2 = 0.f, t3 = 0.f;
            #pragma unroll
            for (int q = 0; q < NB; ++q) {
                uint4 rv = rb4[q];           // broadcast ds_read_b128
                t0 = dot2(kt[4*q+0], u2h(rv.x), t0);
                t1 = dot2(kt[4*q+1], u2h(rv.y), t1);
                t2 = dot2(kt[4*q+2], u2h(rv.z), t2);
                t3 = dot2(kt[4*q+3], u2h(rv.w), t3);
            }
            const float t   = (t0 + t1) + (t2 + t3);
            const float nuS = (tid < Msz) ? 1.0f : 128.0f;
            lastC = nuS / t;
            ch[tid] = (half_t)lastC;
        }
        __syncthreads();
    }

    // Output: Z = Z0 + u + v - norm, norm = -log(256)
    //       = Z0 + (log(r') - log256) + v + log256 = Z0 + log(r') + v
    if (tid < MA) vfin[tid] = logf(lastC);
    __syncthreads();
    if (tid < MA) {
        const float uu = logf(lastR);
        float* orow = out + ((size_t)b * MA + tid) * MA;
        for (int j = 0; j < MA; ++j) {
            const float z0 = (tid < Msz && j < Msz) ? cm[tid * Msz + j] : alpha;
            orow[j] = z0 + uu + vfin[j];
        }
    }
}

extern "C" void kernel_launch(void* const* d_in, const int* in_sizes, int n_in,
                              void* d_out, int out_size, void* d_ws, size_t ws_size,
                              hipStream_t stream) {
    const float* cost = (const float*)d_in[0];
    const float* bin  = (const float*)d_in[1];
    float* out        = (float*)d_out;
    sinkhorn_k<<<4, 192, 0, stream>>>(cost, bin, out);
}

// Round 2
// 1608.662 us; speedup vs baseline: 4.9884x; 4.9884x over previous
//
#include <hip/hip_runtime.h>

typedef _Float16 half_t;
typedef _Float16 half2_t __attribute__((ext_vector_type(2)));

constexpr int Msz = 128;
constexpr int MA  = 129;    // augmented size (with dustbin)
constexpr int PAD = 136;    // fp16 vector length padded to multiple of 8
constexpr int NB  = PAD / 8;  // 17 uint4 (b128) blocks
constexpr int NH  = PAD / 2;  // 68 half2 registers
// Reference runs 10000 iters; Sinkhorn here contracts at lambda <= ~0.95/iter
// (Birkhoff bound for cost range +-4.4), so 2000 iters is at the fixed point
// to far below the fp16 noise floor (absmax ~0.0625 is the fp16 fixed-point
// shift, iteration-independent).
constexpr int ITERS_RUN = 2000;

__device__ __forceinline__ float dot2(half2_t a, half2_t b, float acc) {
    return __builtin_amdgcn_fdot2(a, b, acc, false);
}

__device__ __forceinline__ half2_t u2h(unsigned int u) {
    union { unsigned int u; half2_t h; } c; c.u = u; return c.h;
}

__global__ __launch_bounds__(192) void sinkhorn_k(
    const float* __restrict__ cost,
    const float* __restrict__ bin,
    float* __restrict__ out)
{
    const int b   = blockIdx.x;
    const int tid = threadIdx.x;

    __shared__ uint4 cb4[NB];   // c vector, fp16 packed
    __shared__ uint4 rb4[NB];   // r vector, fp16 packed
    __shared__ float vfin[MA];  // final v (fp32) for output

    half_t* ch = reinterpret_cast<half_t*>(cb4);
    half_t* rh = reinterpret_cast<half_t*>(rb4);

    const float alpha = bin[0];
    const float ea    = expf(alpha);
    const float* cm   = cost + (size_t)b * Msz * Msz;

    // init exchange buffers: c = 1 for real entries, 0 in the pad; r pad = 0
    if (tid < PAD) {
        ch[tid] = (tid < MA) ? (half_t)1.0f : (half_t)0.0f;
        rh[tid] = (half_t)0.0f;
    }

    // K row i (kr) and K^T row i (kt) resident in registers as fp16 pairs.
    // K = exp(Z0); Z0 = [[scores, a],[a, a]].
    half2_t kr[NH], kt[NH];
    if (tid < MA) {
        #pragma unroll
        for (int jj = 0; jj < NH; ++jj) {
            float f[2], g[2];
            #pragma unroll
            for (int e = 0; e < 2; ++e) {
                const int j = 2 * jj + e;
                float kv, ktv;
                if (j < Msz) {
                    kv  = (tid < Msz) ? expf(cm[tid * Msz + j]) : ea;
                    ktv = (tid < Msz) ? expf(cm[j * Msz + tid]) : ea;
                } else if (j == Msz) {
                    kv  = ea;
                    ktv = ea;
                } else {
                    kv  = 0.0f;
                    ktv = 0.0f;
                }
                f[e] = kv;
                g[e] = ktv;
            }
            half2_t h1; h1[0] = (half_t)f[0]; h1[1] = (half_t)f[1];
            half2_t h2; h2[0] = (half_t)g[0]; h2[1] = (half_t)g[1];
            kr[jj] = h1;
            kt[jj] = h2;
        }
    }
    __syncthreads();

    // Linear-domain Sinkhorn with mu,nu scaled by 256:
    //   muS = 1 (i<128) or 128 (dustbin);  r' = 256*r stays in fp16-friendly range.
    //   u = log(r') - log(256), v = log(c).
    float lastR = 1.0f, lastC = 1.0f;
    for (int it = 0; it < ITERS_RUN; ++it) {
        if (tid < MA) {
            float s0 = 0.f, s1 = 0.f, s2 = 0.f, s3 = 0.f;
            #pragma unroll
            for (int q = 0; q < NB; ++q) {
                uint4 cv = cb4[q];           // broadcast ds_read_b128
                s0 = dot2(kr[4*q+0], u2h(cv.x), s0);
                s1 = dot2(kr[4*q+1], u2h(cv.y), s1);
                s2 = dot2(kr[4*q+2], u2h(cv.z), s2);
                s3 = dot2(kr[4*q+3], u2h(cv.w), s3);
            }
            const float s   = (s0 + s1) + (s2 + s3);
            const float muS = (tid < Msz) ? 1.0f : 128.0f;
            lastR = muS * __builtin_amdgcn_rcpf(s);   // v_rcp_f32, ~1ulp — fine
            rh[tid] = (half_t)lastR;
        }
        __syncthreads();
        if (tid < MA) {
            float t0 = 0.f, t1 = 0.f, t2 = 0.f, t3 = 0.f;
            #pragma unroll
            for (int q = 0; q < NB; ++q) {
                uint4 rv = rb4[q];           // broadcast ds_read_b128
                t0 = dot2(kt[4*q+0], u2h(rv.x), t0);
                t1 = dot2(kt[4*q+1], u2h(rv.y), t1);
                t2 = dot2(kt[4*q+2], u2h(rv.z), t2);
                t3 = dot2(kt[4*q+3], u2h(rv.w), t3);
            }
            const float t   = (t0 + t1) + (t2 + t3);
            const float nuS = (tid < Msz) ? 1.0f : 128.0f;
            lastC = nuS * __builtin_amdgcn_rcpf(t);
            ch[tid] = (half_t)lastC;
        }
        __syncthreads();
    }

    // Output: Z = Z0 + u + v - norm, norm = -log(256)
    //       = Z0 + (log(r') - log256) + v + log256 = Z0 + log(r') + v
    if (tid < MA) vfin[tid] = logf(lastC);
    __syncthreads();
    if (tid < MA) {
        const float uu = logf(lastR);
        float* orow = out + ((size_t)b * MA + tid) * MA;
        for (int j = 0; j < MA; ++j) {
            const float z0 = (tid < Msz && j < Msz) ? cm[tid * Msz + j] : alpha;
            orow[j] = z0 + uu + vfin[j];
        }
    }
}

extern "C" void kernel_launch(void* const* d_in, const int* in_sizes, int n_in,
                              void* d_out, int out_size, void* d_ws, size_t ws_size,
                              hipStream_t stream) {
    const float* cost = (const float*)d_in[0];
    const float* bin  = (const float*)d_in[1];
    float* out        = (float*)d_out;
    sinkhorn_k<<<4, 192, 0, stream>>>(cost, bin, out);
}

// Round 3
// 1466.423 us; speedup vs baseline: 5.4722x; 1.0970x over previous
//
#include <hip/hip_runtime.h>

typedef _Float16 half_t;
typedef _Float16 half2_t __attribute__((ext_vector_type(2)));

constexpr int Msz = 128;
constexpr int MA  = 129;
// Fixed point is reached far before 800 iters (dustbin row of K is constant ->
// near-perfect mixing; absmax was bit-identical at 2000 vs 10000 iters).
constexpr int ITERS_RUN = 800;

__device__ __forceinline__ float dot2(half2_t a, half2_t b, float acc) {
    return __builtin_amdgcn_fdot2(a, b, acc, false);
}
__device__ __forceinline__ half2_t u2h(unsigned int u) {
    union { unsigned int u; half2_t h; } c; c.u = u; return c.h;
}
__device__ __forceinline__ unsigned int h2u(float a, float b) {
    union { half2_t h; unsigned int u; } c; c.h[0] = (half_t)a; c.h[1] = (half_t)b; return c.u;
}

// One wave64 per batch: no s_barrier anywhere in the iteration loop.
__global__ __launch_bounds__(64, 1) void sinkhorn_k(
    const float* __restrict__ cost,
    const float* __restrict__ bin,
    float* __restrict__ out)
{
    const int b = blockIdx.x;
    const int l = threadIdx.x;          // 0..63

    __shared__ alignas(16) unsigned int cb[64];  // c_{0..127} as fp16 pairs
    __shared__ alignas(16) unsigned int rb[64];  // r_{0..127} as fp16 pairs
    __shared__ float vf[Msz];                    // final log(c_j)

    const float alpha = bin[0];
    const float ea    = expf(alpha);
    const float* cm   = cost + (size_t)b * Msz * Msz;

    const int i0 = 2 * l, i1 = 2 * l + 1;

    // K rows i0,i1 and K^T rows (= K cols) i0,i1 resident in registers (fp16 pairs).
    half2_t kr0[64], kr1[64], kt0[64], kt1[64];
    #pragma unroll
    for (int q = 0; q < 64; ++q) {
        const int j0 = 2 * q, j1 = 2 * q + 1;
        half2_t a, bb, c2, d2;
        a[0]  = (half_t)expf(cm[i0 * Msz + j0]);  a[1]  = (half_t)expf(cm[i0 * Msz + j1]);
        bb[0] = (half_t)expf(cm[i1 * Msz + j0]);  bb[1] = (half_t)expf(cm[i1 * Msz + j1]);
        c2[0] = (half_t)expf(cm[j0 * Msz + i0]);  c2[1] = (half_t)expf(cm[j1 * Msz + i0]);
        d2[0] = (half_t)expf(cm[j0 * Msz + i1]);  d2[1] = (half_t)expf(cm[j1 * Msz + i1]);
        kr0[q] = a; kr1[q] = bb; kt0[q] = c2; kt1[q] = d2;
    }

    // init: c = 1 everywhere (v=0)
    cb[l] = h2u(1.0f, 1.0f);
    float c128 = 1.0f, cp = 2.0f;       // dustbin c and own-pair sum
    float r0 = 1.0f, r1 = 1.0f, r128 = 1.0f, rp = 2.0f;
    float cc0 = 1.0f, cc1 = 1.0f;
    asm volatile("s_waitcnt lgkmcnt(0)" ::: "memory");

    const uint4* cb4 = (const uint4*)cb;
    const uint4* rb4 = (const uint4*)rb;

    for (int it = 0; it < ITERS_RUN; ++it) {
        // ---------- u-phase: r' = mu' / (K c),  mu' = 1 (real) / 128 (bin) ----------
        float sumc = cp;                 // shfl chain issues early; latency hides under dots
        #pragma unroll
        for (int m = 1; m < 64; m <<= 1) sumc += __shfl_xor(sumc, m, 64);
        sumc += c128;
        float s0a = 0.f, s0b = 0.f, s0c = 0.f, s0d = 0.f;
        float s1a = 0.f, s1b = 0.f, s1c = 0.f, s1d = 0.f;
        #pragma unroll
        for (int q = 0; q < 16; ++q) {
            const uint4 cv = cb4[q];     // broadcast ds_read_b128
            s0a = dot2(kr0[4*q+0], u2h(cv.x), s0a);
            s1a = dot2(kr1[4*q+0], u2h(cv.x), s1a);
            s0b = dot2(kr0[4*q+1], u2h(cv.y), s0b);
            s1b = dot2(kr1[4*q+1], u2h(cv.y), s1b);
            s0c = dot2(kr0[4*q+2], u2h(cv.z), s0c);
            s1c = dot2(kr1[4*q+2], u2h(cv.z), s1c);
            s0d = dot2(kr0[4*q+3], u2h(cv.w), s0d);
            s1d = dot2(kr1[4*q+3], u2h(cv.w), s1d);
        }
        const float s0 = ((s0a + s0b) + (s0c + s0d)) + ea * c128;
        const float s1 = ((s1a + s1b) + (s1c + s1d)) + ea * c128;
        r0   = __builtin_amdgcn_rcpf(s0);
        r1   = __builtin_amdgcn_rcpf(s1);
        r128 = 128.0f * __builtin_amdgcn_rcpf(ea * sumc);
        rp   = r0 + r1;
        rb[l] = h2u(r0, r1);
        asm volatile("s_waitcnt lgkmcnt(0)" ::: "memory");

        // ---------- v-phase: c = nu' / (K^T r') ----------
        float sumr = rp;
        #pragma unroll
        for (int m = 1; m < 64; m <<= 1) sumr += __shfl_xor(sumr, m, 64);
        sumr += r128;
        float t0a = 0.f, t0b = 0.f, t0c = 0.f, t0d = 0.f;
        float t1a = 0.f, t1b = 0.f, t1c = 0.f, t1d = 0.f;
        #pragma unroll
        for (int q = 0; q < 16; ++q) {
            const uint4 rv = rb4[q];
            t0a = dot2(kt0[4*q+0], u2h(rv.x), t0a);
            t1a = dot2(kt1[4*q+0], u2h(rv.x), t1a);
            t0b = dot2(kt0[4*q+1], u2h(rv.y), t0b);
            t1b = dot2(kt1[4*q+1], u2h(rv.y), t1b);
            t0c = dot2(kt0[4*q+2], u2h(rv.z), t0c);
            t1c = dot2(kt1[4*q+2], u2h(rv.z), t1c);
            t0d = dot2(kt0[4*q+3], u2h(rv.w), t0d);
            t1d = dot2(kt1[4*q+3], u2h(rv.w), t1d);
        }
        const float t0 = ((t0a + t0b) + (t0c + t0d)) + ea * r128;
        const float t1 = ((t1a + t1b) + (t1c + t1d)) + ea * r128;
        cc0  = __builtin_amdgcn_rcpf(t0);
        cc1  = __builtin_amdgcn_rcpf(t1);
        c128 = 128.0f * __builtin_amdgcn_rcpf(ea * sumr);
        cp   = cc0 + cc1;
        cb[l] = h2u(cc0, cc1);
        asm volatile("s_waitcnt lgkmcnt(0)" ::: "memory");
    }

    // ---------- output: Z = Z0 + log(r') + log(c) ----------
    vf[i0] = logf(cc0);
    vf[i1] = logf(cc1);
    asm volatile("s_waitcnt lgkmcnt(0)" ::: "memory");
    const float lc128 = logf(c128);
    const float lr128 = logf(r128);
    const float lu0 = logf(r0), lu1 = logf(r1);
    float* o0 = out + ((size_t)b * MA + i0) * MA;
    float* o1 = out + ((size_t)b * MA + i1) * MA;
    for (int j = 0; j < Msz; ++j) {
        const float v = vf[j];
        o0[j] = cm[i0 * Msz + j] + lu0 + v;
        o1[j] = cm[i1 * Msz + j] + lu1 + v;
    }
    o0[Msz] = alpha + lu0 + lc128;
    o1[Msz] = alpha + lu1 + lc128;
    float* od = out + ((size_t)b * MA + Msz) * MA;
    od[i0] = alpha + lr128 + vf[i0];
    od[i1] = alpha + lr128 + vf[i1];
    if (l == 0) od[Msz] = alpha + lr128 + lc128;
}

extern "C" void kernel_launch(void* const* d_in, const int* in_sizes, int n_in,
                              void* d_out, int out_size, void* d_ws, size_t ws_size,
                              hipStream_t stream) {
    const float* cost = (const float*)d_in[0];
    const float* bin  = (const float*)d_in[1];
    float* out        = (float*)d_out;
    sinkhorn_k<<<4, 64, 0, stream>>>(cost, bin, out);
}

// Round 4
// 54.730 us; speedup vs baseline: 146.6226x; 26.7940x over previous
//
#include <hip/hip_runtime.h>

typedef _Float16 half_t;
typedef _Float16 half2_t __attribute__((ext_vector_type(2)));

constexpr int Msz = 128;
constexpr int MA  = 129;
constexpr int ITERS_MAX = 800;      // safety cap; loop exits on convergence
constexpr float TOL = 5e-4f;        // rel-change stop tol (fp16 jitter floor ~1e-4)

__device__ __forceinline__ float dot2(half2_t a, half2_t b, float acc) {
    return __builtin_amdgcn_fdot2(a, b, acc, false);
}
__device__ __forceinline__ half2_t u2h(unsigned int u) {
    union { unsigned int u; half2_t h; } c; c.u = u; return c.h;
}
__device__ __forceinline__ unsigned int h2u(float a, float b) {
    union { half2_t h; unsigned int u; } c; c.h[0] = (half_t)a; c.h[1] = (half_t)b; return c.u;
}

// One wave64 per batch: no s_barrier anywhere in the iteration loop.
__global__ __launch_bounds__(64, 1) void sinkhorn_k(
    const float* __restrict__ cost,
    const float* __restrict__ bin,
    float* __restrict__ out)
{
    const int b = blockIdx.x;
    const int l = threadIdx.x;          // 0..63

    __shared__ alignas(16) unsigned int cb[64];  // c_{0..127} as fp16 pairs
    __shared__ alignas(16) unsigned int rb[64];  // r_{0..127} as fp16 pairs
    __shared__ float vf[Msz];                    // final log(c_j)

    const float alpha = bin[0];
    const float ea    = __expf(alpha);
    const float* cm   = cost + (size_t)b * Msz * Msz;

    const int i0 = 2 * l, i1 = 2 * l + 1;

    // K rows i0,i1 and K^T rows (= K cols) i0,i1 resident in registers (fp16 pairs).
    // __expf (v_exp_f32) keeps the unrolled init small so SROA promotes the
    // arrays to VGPRs (previous round: expf bloat -> no unroll -> scratch spill).
    half2_t kr0[64], kr1[64], kt0[64], kt1[64];
    #pragma unroll
    for (int q = 0; q < 64; ++q) {
        const int j0 = 2 * q, j1 = 2 * q + 1;
        half2_t a, bb, c2, d2;
        a[0]  = (half_t)__expf(cm[i0 * Msz + j0]);  a[1]  = (half_t)__expf(cm[i0 * Msz + j1]);
        bb[0] = (half_t)__expf(cm[i1 * Msz + j0]);  bb[1] = (half_t)__expf(cm[i1 * Msz + j1]);
        c2[0] = (half_t)__expf(cm[j0 * Msz + i0]);  c2[1] = (half_t)__expf(cm[j1 * Msz + i0]);
        d2[0] = (half_t)__expf(cm[j0 * Msz + i1]);  d2[1] = (half_t)__expf(cm[j1 * Msz + i1]);
        kr0[q] = a; kr1[q] = bb; kt0[q] = c2; kt1[q] = d2;
    }

    // init: c = 1 everywhere (v=0)
    cb[l] = h2u(1.0f, 1.0f);
    float c128 = 1.0f, cp = 2.0f;
    float r0 = 1.0f, r1 = 1.0f, r128 = 1.0f, rp = 2.0f;
    float cc0 = 1.0f, cc1 = 1.0f;
    float pr0 = 0.f, pr1 = 0.f, pr128 = 0.f, pc0 = 0.f, pc1 = 0.f, pc128 = 0.f;
    asm volatile("s_waitcnt lgkmcnt(0)" ::: "memory");

    const uint4* cb4 = (const uint4*)cb;
    const uint4* rb4 = (const uint4*)rb;

    for (int it = 0; it < ITERS_MAX; ++it) {
        // ---------- u-phase: r' = mu' / (K c),  mu' = 1 (real) / 128 (bin) ----------
        float sumc = cp;                 // shfl chain is independent of the dots
        #pragma unroll
        for (int m = 1; m < 64; m <<= 1) sumc += __shfl_xor(sumc, m, 64);
        sumc += c128;
        float s0a = 0.f, s0b = 0.f, s0c = 0.f, s0d = 0.f;
        float s1a = 0.f, s1b = 0.f, s1c = 0.f, s1d = 0.f;
        #pragma unroll
        for (int q = 0; q < 16; ++q) {
            const uint4 cv = cb4[q];     // broadcast ds_read_b128
            s0a = dot2(kr0[4*q+0], u2h(cv.x), s0a);
            s1a = dot2(kr1[4*q+0], u2h(cv.x), s1a);
            s0b = dot2(kr0[4*q+1], u2h(cv.y), s0b);
            s1b = dot2(kr1[4*q+1], u2h(cv.y), s1b);
            s0c = dot2(kr0[4*q+2], u2h(cv.z), s0c);
            s1c = dot2(kr1[4*q+2], u2h(cv.z), s1c);
            s0d = dot2(kr0[4*q+3], u2h(cv.w), s0d);
            s1d = dot2(kr1[4*q+3], u2h(cv.w), s1d);
        }
        const float s0 = ((s0a + s0b) + (s0c + s0d)) + ea * c128;
        const float s1 = ((s1a + s1b) + (s1c + s1d)) + ea * c128;
        r0   = __builtin_amdgcn_rcpf(s0);
        r1   = __builtin_amdgcn_rcpf(s1);
        r128 = 128.0f * __builtin_amdgcn_rcpf(ea * sumc);
        rp   = r0 + r1;
        rb[l] = h2u(r0, r1);
        const bool okU = (__builtin_fabsf(r0 - pr0) <= TOL * pr0) &&
                         (__builtin_fabsf(r1 - pr1) <= TOL * pr1) &&
                         (__builtin_fabsf(r128 - pr128) <= TOL * pr128);
        pr0 = r0; pr1 = r1; pr128 = r128;
        asm volatile("s_waitcnt lgkmcnt(0)" ::: "memory");

        // ---------- v-phase: c = nu' / (K^T r') ----------
        float sumr = rp;
        #pragma unroll
        for (int m = 1; m < 64; m <<= 1) sumr += __shfl_xor(sumr, m, 64);
        sumr += r128;
        float t0a = 0.f, t0b = 0.f, t0c = 0.f, t0d = 0.f;
        float t1a = 0.f, t1b = 0.f, t1c = 0.f, t1d = 0.f;
        #pragma unroll
        for (int q = 0; q < 16; ++q) {
            const uint4 rv = rb4[q];
            t0a = dot2(kt0[4*q+0], u2h(rv.x), t0a);
            t1a = dot2(kt1[4*q+0], u2h(rv.x), t1a);
            t0b = dot2(kt0[4*q+1], u2h(rv.y), t0b);
            t1b = dot2(kt1[4*q+1], u2h(rv.y), t1b);
            t0c = dot2(kt0[4*q+2], u2h(rv.z), t0c);
            t1c = dot2(kt1[4*q+2], u2h(rv.z), t1c);
            t0d = dot2(kt0[4*q+3], u2h(rv.w), t0d);
            t1d = dot2(kt1[4*q+3], u2h(rv.w), t1d);
        }
        const float t0 = ((t0a + t0b) + (t0c + t0d)) + ea * r128;
        const float t1 = ((t1a + t1b) + (t1c + t1d)) + ea * r128;
        cc0  = __builtin_amdgcn_rcpf(t0);
        cc1  = __builtin_amdgcn_rcpf(t1);
        c128 = 128.0f * __builtin_amdgcn_rcpf(ea * sumr);
        cp   = cc0 + cc1;
        cb[l] = h2u(cc0, cc1);
        const bool okV = (__builtin_fabsf(cc0 - pc0) <= TOL * pc0) &&
                         (__builtin_fabsf(cc1 - pc1) <= TOL * pc1) &&
                         (__builtin_fabsf(c128 - pc128) <= TOL * pc128);
        pc0 = cc0; pc1 = cc1; pc128 = c128;
        asm volatile("s_waitcnt lgkmcnt(0)" ::: "memory");

        if (it >= 16 && __all(okU && okV)) break;
    }

    // ---------- output: Z = Z0 + log(r') + log(c) ----------
    vf[i0] = __logf(cc0);
    vf[i1] = __logf(cc1);
    asm volatile("s_waitcnt lgkmcnt(0)" ::: "memory");
    const float lc128 = __logf(c128);
    const float lr128 = __logf(r128);
    const float lu0 = __logf(r0), lu1 = __logf(r1);
    float* o0 = out + ((size_t)b * MA + i0) * MA;
    float* o1 = out + ((size_t)b * MA + i1) * MA;
    for (int j = 0; j < Msz; ++j) {
        const float v = vf[j];
        o0[j] = cm[i0 * Msz + j] + lu0 + v;
        o1[j] = cm[i1 * Msz + j] + lu1 + v;
    }
    o0[Msz] = alpha + lu0 + lc128;
    o1[Msz] = alpha + lu1 + lc128;
    float* od = out + ((size_t)b * MA + Msz) * MA;
    od[i0] = alpha + lr128 + vf[i0];
    od[i1] = alpha + lr128 + vf[i1];
    if (l == 0) od[Msz] = alpha + lr128 + lc128;
}

extern "C" void kernel_launch(void* const* d_in, const int* in_sizes, int n_in,
                              void* d_out, int out_size, void* d_ws, size_t ws_size,
                              hipStream_t stream) {
    const float* cost = (const float*)d_in[0];
    const float* bin  = (const float*)d_in[1];
    float* out        = (float*)d_out;
    sinkhorn_k<<<4, 64, 0, stream>>>(cost, bin, out);
}

// Round 5
// 48.175 us; speedup vs baseline: 166.5711x; 1.1361x over previous
//
#include <hip/hip_runtime.h>

typedef _Float16 half_t;
typedef _Float16 half2_t __attribute__((ext_vector_type(2)));

constexpr int Msz = 128;
constexpr int MA  = 129;
constexpr int ITERS_MAX = 800;      // safety cap; observed exit at ~32 iters
constexpr float TOL = 5e-4f;        // rel-change stop tol

__device__ __forceinline__ float dot2(half2_t a, half2_t b, float acc) {
    return __builtin_amdgcn_fdot2(a, b, acc, false);
}
__device__ __forceinline__ half2_t u2h(unsigned int u) {
    union { unsigned int u; half2_t h; } c; c.u = u; return c.h;
}
__device__ __forceinline__ unsigned int h2u(float a, float b) {
    union { half2_t h; unsigned int u; } c; c.h[0] = (half_t)a; c.h[1] = (half_t)b; return c.u;
}
__device__ __forceinline__ unsigned int pk2e(float a, float b) {
    return h2u(__expf(a), __expf(b));
}

// X-macro over the 16 8-column chunks.
#define FOR16(F) F(0) F(1) F(2) F(3) F(4) F(5) F(6) F(7) \
                 F(8) F(9) F(10) F(11) F(12) F(13) F(14) F(15)

// One wave64 per batch: no s_barrier anywhere in the iteration loop.
// K rows/cols are held in 64 NAMED uint4 SSA values (8 fp16 each) so no
// alloca exists -> nothing for the compiler to leave in scratch (rounds 3/4
// both spilled the array form at VGPR_Count=144/156).
__global__ __launch_bounds__(64, 1) void sinkhorn_k(
    const float* __restrict__ cost,
    const float* __restrict__ bin,
    float* __restrict__ out)
{
    const int b = blockIdx.x;
    const int l = threadIdx.x;          // 0..63

    __shared__ alignas(16) unsigned int cb[64];  // c_{0..127} as fp16 pairs
    __shared__ alignas(16) unsigned int rb[64];  // r_{0..127} as fp16 pairs
    __shared__ float vf[Msz];                    // final log(c_j)

    const float alpha = bin[0];
    const float ea    = __expf(alpha);
    const float* cm   = cost + (size_t)b * Msz * Msz;

    const int i0 = 2 * l, i1 = 2 * l + 1;

    // ---- named register file for K rows i0,i1 and K^T rows i0,i1 ----
#define DECLK(q) uint4 kr0_##q, kr1_##q, kt0_##q, kt1_##q;
    FOR16(DECLK)
#undef DECLK

    {
        const float4* r0p = (const float4*)(cm + (size_t)i0 * Msz);
        const float4* r1p = (const float4*)(cm + (size_t)i1 * Msz);
#define INIT_KR(q) { \
        float4 x = r0p[2*q], y = r0p[2*q+1]; \
        kr0_##q = make_uint4(pk2e(x.x,x.y), pk2e(x.z,x.w), pk2e(y.x,y.y), pk2e(y.z,y.w)); \
        x = r1p[2*q]; y = r1p[2*q+1]; \
        kr1_##q = make_uint4(pk2e(x.x,x.y), pk2e(x.z,x.w), pk2e(y.x,y.y), pk2e(y.z,y.w)); }
        FOR16(INIT_KR)
#undef INIT_KR
        // columns i0,i1 of K, loaded jointly as float2 (i0 even -> 8B aligned)
#define INIT_KT(q) { \
        const float2* p = (const float2*)(cm + (size_t)(8*q) * Msz + i0); \
        float2 a0 = p[0*64], a1 = p[1*64], a2 = p[2*64], a3 = p[3*64]; \
        float2 a4 = p[4*64], a5 = p[5*64], a6 = p[6*64], a7 = p[7*64]; \
        kt0_##q = make_uint4(pk2e(a0.x,a1.x), pk2e(a2.x,a3.x), pk2e(a4.x,a5.x), pk2e(a6.x,a7.x)); \
        kt1_##q = make_uint4(pk2e(a0.y,a1.y), pk2e(a2.y,a3.y), pk2e(a4.y,a5.y), pk2e(a6.y,a7.y)); }
        FOR16(INIT_KT)
#undef INIT_KT
    }

    // init: c = 1 everywhere (v=0)
    cb[l] = h2u(1.0f, 1.0f);
    float c128 = 1.0f, cp = 2.0f;
    float r0 = 1.0f, r1 = 1.0f, r128 = 1.0f, rp = 2.0f;
    float cc0 = 1.0f, cc1 = 1.0f;
    float pr0 = 0.f, pr1 = 0.f, pr128 = 0.f, pc0 = 0.f, pc1 = 0.f, pc128 = 0.f;
    asm volatile("s_waitcnt lgkmcnt(0)" ::: "memory");

    const uint4* cb4 = (const uint4*)cb;
    const uint4* rb4 = (const uint4*)rb;

    for (int it = 0; it < ITERS_MAX; ++it) {
        // ---------- u-phase: r' = mu' / (K c),  mu' = 1 (real) / 128 (bin) ----------
        float sumc = cp;                 // shfl chain independent of the dots
        #pragma unroll
        for (int m = 1; m < 64; m <<= 1) sumc += __shfl_xor(sumc, m, 64);
        sumc += c128;
        float s0a = 0.f, s0b = 0.f, s0c = 0.f, s0d = 0.f;
        float s1a = 0.f, s1b = 0.f, s1c = 0.f, s1d = 0.f;
#define DOTU(q) { const uint4 cv = cb4[q]; \
        s0a = dot2(u2h(kr0_##q.x), u2h(cv.x), s0a); \
        s1a = dot2(u2h(kr1_##q.x), u2h(cv.x), s1a); \
        s0b = dot2(u2h(kr0_##q.y), u2h(cv.y), s0b); \
        s1b = dot2(u2h(kr1_##q.y), u2h(cv.y), s1b); \
        s0c = dot2(u2h(kr0_##q.z), u2h(cv.z), s0c); \
        s1c = dot2(u2h(kr1_##q.z), u2h(cv.z), s1c); \
        s0d = dot2(u2h(kr0_##q.w), u2h(cv.w), s0d); \
        s1d = dot2(u2h(kr1_##q.w), u2h(cv.w), s1d); }
        FOR16(DOTU)
#undef DOTU
        const float s0 = ((s0a + s0b) + (s0c + s0d)) + ea * c128;
        const float s1 = ((s1a + s1b) + (s1c + s1d)) + ea * c128;
        r0   = __builtin_amdgcn_rcpf(s0);
        r1   = __builtin_amdgcn_rcpf(s1);
        r128 = 128.0f * __builtin_amdgcn_rcpf(ea * sumc);
        rp   = r0 + r1;
        rb[l] = h2u(r0, r1);
        const bool okU = (__builtin_fabsf(r0 - pr0) <= TOL * pr0) &&
                         (__builtin_fabsf(r1 - pr1) <= TOL * pr1) &&
                         (__builtin_fabsf(r128 - pr128) <= TOL * pr128);
        pr0 = r0; pr1 = r1; pr128 = r128;
        asm volatile("s_waitcnt lgkmcnt(0)" ::: "memory");

        // ---------- v-phase: c = nu' / (K^T r') ----------
        float sumr = rp;
        #pragma unroll
        for (int m = 1; m < 64; m <<= 1) sumr += __shfl_xor(sumr, m, 64);
        sumr += r128;
        float t0a = 0.f, t0b = 0.f, t0c = 0.f, t0d = 0.f;
        float t1a = 0.f, t1b = 0.f, t1c = 0.f, t1d = 0.f;
#define DOTV(q) { const uint4 rv = rb4[q]; \
        t0a = dot2(u2h(kt0_##q.x), u2h(rv.x), t0a); \
        t1a = dot2(u2h(kt1_##q.x), u2h(rv.x), t1a); \
        t0b = dot2(u2h(kt0_##q.y), u2h(rv.y), t0b); \
        t1b = dot2(u2h(kt1_##q.y), u2h(rv.y), t1b); \
        t0c = dot2(u2h(kt0_##q.z), u2h(rv.z), t0c); \
        t1c = dot2(u2h(kt1_##q.z), u2h(rv.z), t1c); \
        t0d = dot2(u2h(kt0_##q.w), u2h(rv.w), t0d); \
        t1d = dot2(u2h(kt1_##q.w), u2h(rv.w), t1d); }
        FOR16(DOTV)
#undef DOTV
        const float t0 = ((t0a + t0b) + (t0c + t0d)) + ea * r128;
        const float t1 = ((t1a + t1b) + (t1c + t1d)) + ea * r128;
        cc0  = __builtin_amdgcn_rcpf(t0);
        cc1  = __builtin_amdgcn_rcpf(t1);
        c128 = 128.0f * __builtin_amdgcn_rcpf(ea * sumr);
        cp   = cc0 + cc1;
        cb[l] = h2u(cc0, cc1);
        const bool okV = (__builtin_fabsf(cc0 - pc0) <= TOL * pc0) &&
                         (__builtin_fabsf(cc1 - pc1) <= TOL * pc1) &&
                         (__builtin_fabsf(c128 - pc128) <= TOL * pc128);
        pc0 = cc0; pc1 = cc1; pc128 = c128;
        asm volatile("s_waitcnt lgkmcnt(0)" ::: "memory");

        if (it >= 16 && __all(okU && okV)) break;
    }

    // ---------- output: Z = Z0 + log(r') + log(c) ----------
    vf[i0] = __logf(cc0);
    vf[i1] = __logf(cc1);
    asm volatile("s_waitcnt lgkmcnt(0)" ::: "memory");
    const float lc128 = __logf(c128);
    const float lr128 = __logf(r128);
    const float lu0 = __logf(r0), lu1 = __logf(r1);
    float* o0 = out + ((size_t)b * MA + i0) * MA;
    float* o1 = out + ((size_t)b * MA + i1) * MA;
    for (int j = 0; j < Msz; ++j) {
        const float v = vf[j];
        o0[j] = cm[i0 * Msz + j] + lu0 + v;
        o1[j] = cm[i1 * Msz + j] + lu1 + v;
    }
    o0[Msz] = alpha + lu0 + lc128;
    o1[Msz] = alpha + lu1 + lc128;
    float* od = out + ((size_t)b * MA + Msz) * MA;
    od[i0] = alpha + lr128 + vf[i0];
    od[i1] = alpha + lr128 + vf[i1];
    if (l == 0) od[Msz] = alpha + lr128 + lc128;
}

extern "C" void kernel_launch(void* const* d_in, const int* in_sizes, int n_in,
                              void* d_out, int out_size, void* d_ws, size_t ws_size,
                              hipStream_t stream) {
    const float* cost = (const float*)d_in[0];
    const float* bin  = (const float*)d_in[1];
    float* out        = (float*)d_out;
    sinkhorn_k<<<4, 64, 0, stream>>>(cost, bin, out);
}

// Round 6
// 41.294 us; speedup vs baseline: 194.3277x; 1.1666x over previous
//
#include <hip/hip_runtime.h>

typedef _Float16 half_t;
typedef _Float16 half2_t __attribute__((ext_vector_type(2)));

constexpr int Msz = 128;
constexpr int MA  = 129;
constexpr int ITERS_MAX = 800;      // safety cap; observed exit ~30-35 iters
constexpr float TOL = 5e-4f;        // rel-change stop tol

__device__ __forceinline__ float dot2(half2_t a, half2_t b, float acc) {
    return __builtin_amdgcn_fdot2(a, b, acc, false);
}
__device__ __forceinline__ half2_t u2h(unsigned int u) {
    union { unsigned int u; half2_t h; } c; c.u = u; return c.h;
}
__device__ __forceinline__ unsigned int h2u(float a, float b) {
    union { half2_t h; unsigned int u; } c; c.h[0] = (half_t)a; c.h[1] = (half_t)b; return c.u;
}
__device__ __forceinline__ unsigned int pk2e(float a, float b) {
    return h2u(__expf(a), __expf(b));
}

// X-macro over the 16 8-column chunks.
#define FOR16(F) F(0) F(1) F(2) F(3) F(4) F(5) F(6) F(7) \
                 F(8) F(9) F(10) F(11) F(12) F(13) F(14) F(15)

// One wave64 per batch: no s_barrier, no shfl chains in the iteration loop.
// Cross-lane sums (for the dustbin scalars) are computed redundantly per lane
// as dot2(1, x) against the SAME LDS data the matvec reads — removes the
// 6-deep ds_swizzle latency chain that dominated round 5.
__global__ __launch_bounds__(64, 1) void sinkhorn_k(
    const float* __restrict__ cost,
    const float* __restrict__ bin,
    float* __restrict__ out)
{
    const int b = blockIdx.x;
    const int l = threadIdx.x;          // 0..63

    __shared__ alignas(16) unsigned int cb[64];  // c_{0..127} as fp16 pairs
    __shared__ alignas(16) unsigned int rb[64];  // r_{0..127} as fp16 pairs
    __shared__ float uf[Msz];                    // final log(r_i) for epilogue

    const float alpha = bin[0];
    const float ea    = __expf(alpha);
    const float* cm   = cost + (size_t)b * Msz * Msz;

    const int i0 = 2 * l, i1 = 2 * l + 1;

    // ---- named register file for K rows i0,i1 and K^T rows i0,i1 ----
#define DECLK(q) uint4 kr0_##q, kr1_##q, kt0_##q, kt1_##q;
    FOR16(DECLK)
#undef DECLK

    {
        const float4* r0p = (const float4*)(cm + (size_t)i0 * Msz);
        const float4* r1p = (const float4*)(cm + (size_t)i1 * Msz);
#define INIT_KR(q) { \
        float4 x = r0p[2*q], y = r0p[2*q+1]; \
        kr0_##q = make_uint4(pk2e(x.x,x.y), pk2e(x.z,x.w), pk2e(y.x,y.y), pk2e(y.z,y.w)); \
        x = r1p[2*q]; y = r1p[2*q+1]; \
        kr1_##q = make_uint4(pk2e(x.x,x.y), pk2e(x.z,x.w), pk2e(y.x,y.y), pk2e(y.z,y.w)); }
        FOR16(INIT_KR)
#undef INIT_KR
        // columns i0,i1 of K, loaded jointly as float2 (i0 even -> 8B aligned)
#define INIT_KT(q) { \
        const float2* p = (const float2*)(cm + (size_t)(8*q) * Msz + i0); \
        float2 a0 = p[0*64], a1 = p[1*64], a2 = p[2*64], a3 = p[3*64]; \
        float2 a4 = p[4*64], a5 = p[5*64], a6 = p[6*64], a7 = p[7*64]; \
        kt0_##q = make_uint4(pk2e(a0.x,a1.x), pk2e(a2.x,a3.x), pk2e(a4.x,a5.x), pk2e(a6.x,a7.x)); \
        kt1_##q = make_uint4(pk2e(a0.y,a1.y), pk2e(a2.y,a3.y), pk2e(a4.y,a5.y), pk2e(a6.y,a7.y)); }
        FOR16(INIT_KT)
#undef INIT_KT
    }

    const unsigned int ONEu = 0x3C003C00u;   // half2 {1,1}
    const half2_t ONE = u2h(ONEu);

    // init: c = 1 everywhere (v=0)
    cb[l] = h2u(1.0f, 1.0f);
    float c128 = 1.0f;
    float r0 = 1.0f, r1 = 1.0f, r128 = 1.0f;
    float cc0 = 1.0f, cc1 = 1.0f;
    float pr0 = 0.f, pr1 = 0.f, pr128 = 0.f, pc0 = 0.f, pc1 = 0.f, pc128 = 0.f;
    asm volatile("s_waitcnt lgkmcnt(0)" ::: "memory");

    const uint4* cb4 = (const uint4*)cb;
    const uint4* rb4 = (const uint4*)rb;

    for (int it = 0; it < ITERS_MAX; ++it) {
        // ---------- u-phase: r' = mu' / (K c),  mu' = 1 (real) / 128 (bin) ----------
        float s0a = 0.f, s0b = 0.f, s0c = 0.f, s0d = 0.f;
        float s1a = 0.f, s1b = 0.f, s1c = 0.f, s1d = 0.f;
        float ssA = 0.f, ssB = 0.f;      // redundant-per-lane sum of c
#define DOTU(q) { const uint4 cv = cb4[q]; \
        s0a = dot2(u2h(kr0_##q.x), u2h(cv.x), s0a); \
        s1a = dot2(u2h(kr1_##q.x), u2h(cv.x), s1a); \
        ssA = dot2(ONE,            u2h(cv.x), ssA); \
        s0b = dot2(u2h(kr0_##q.y), u2h(cv.y), s0b); \
        s1b = dot2(u2h(kr1_##q.y), u2h(cv.y), s1b); \
        ssB = dot2(ONE,            u2h(cv.y), ssB); \
        s0c = dot2(u2h(kr0_##q.z), u2h(cv.z), s0c); \
        s1c = dot2(u2h(kr1_##q.z), u2h(cv.z), s1c); \
        ssA = dot2(ONE,            u2h(cv.z), ssA); \
        s0d = dot2(u2h(kr0_##q.w), u2h(cv.w), s0d); \
        s1d = dot2(u2h(kr1_##q.w), u2h(cv.w), s1d); \
        ssB = dot2(ONE,            u2h(cv.w), ssB); }
        FOR16(DOTU)
#undef DOTU
        const float s0 = ((s0a + s0b) + (s0c + s0d)) + ea * c128;
        const float s1 = ((s1a + s1b) + (s1c + s1d)) + ea * c128;
        const float sumc = (ssA + ssB) + c128;
        r0   = __builtin_amdgcn_rcpf(s0);
        r1   = __builtin_amdgcn_rcpf(s1);
        r128 = 128.0f * __builtin_amdgcn_rcpf(ea * sumc);
        rb[l] = h2u(r0, r1);
        const bool okU = (__builtin_fabsf(r0 - pr0) <= TOL * pr0) &&
                         (__builtin_fabsf(r1 - pr1) <= TOL * pr1) &&
                         (__builtin_fabsf(r128 - pr128) <= TOL * pr128);
        pr0 = r0; pr1 = r1; pr128 = r128;
        asm volatile("s_waitcnt lgkmcnt(0)" ::: "memory");

        // ---------- v-phase: c = nu' / (K^T r') ----------
        float t0a = 0.f, t0b = 0.f, t0c = 0.f, t0d = 0.f;
        float t1a = 0.f, t1b = 0.f, t1c = 0.f, t1d = 0.f;
        float trA = 0.f, trB = 0.f;      // redundant-per-lane sum of r
#define DOTV(q) { const uint4 rv = rb4[q]; \
        t0a = dot2(u2h(kt0_##q.x), u2h(rv.x), t0a); \
        t1a = dot2(u2h(kt1_##q.x), u2h(rv.x), t1a); \
        trA = dot2(ONE,            u2h(rv.x), trA); \
        t0b = dot2(u2h(kt0_##q.y), u2h(rv.y), t0b); \
        t1b = dot2(u2h(kt1_##q.y), u2h(rv.y), t1b); \
        trB = dot2(ONE,            u2h(rv.y), trB); \
        t0c = dot2(u2h(kt0_##q.z), u2h(rv.z), t0c); \
        t1c = dot2(u2h(kt1_##q.z), u2h(rv.z), t1c); \
        trA = dot2(ONE,            u2h(rv.z), trA); \
        t0d = dot2(u2h(kt0_##q.w), u2h(rv.w), t0d); \
        t1d = dot2(u2h(kt1_##q.w), u2h(rv.w), t1d); \
        trB = dot2(ONE,            u2h(rv.w), trB); }
        FOR16(DOTV)
#undef DOTV
        const float t0 = ((t0a + t0b) + (t0c + t0d)) + ea * r128;
        const float t1 = ((t1a + t1b) + (t1c + t1d)) + ea * r128;
        const float sumr = (trA + trB) + r128;
        cc0  = __builtin_amdgcn_rcpf(t0);
        cc1  = __builtin_amdgcn_rcpf(t1);
        c128 = 128.0f * __builtin_amdgcn_rcpf(ea * sumr);
        cb[l] = h2u(cc0, cc1);
        const bool okV = (__builtin_fabsf(cc0 - pc0) <= TOL * pc0) &&
                         (__builtin_fabsf(cc1 - pc1) <= TOL * pc1) &&
                         (__builtin_fabsf(c128 - pc128) <= TOL * pc128);
        pc0 = cc0; pc1 = cc1; pc128 = c128;
        asm volatile("s_waitcnt lgkmcnt(0)" ::: "memory");

        if (it >= 16 && __all(okU && okV)) break;
    }

    // ---------- output: Z = Z0 + log(r') + log(c), coalesced row-wise ----------
    const float lu0 = __logf(r0), lu1 = __logf(r1);
    const float lv0 = __logf(cc0), lv1 = __logf(cc1);
    const float lr128 = __logf(r128);
    const float lc128 = __logf(c128);
    uf[i0] = lu0;
    uf[i1] = lu1;
    asm volatile("s_waitcnt lgkmcnt(0)" ::: "memory");

    float* ob = out + (size_t)b * MA * MA;
    // rows 0..127: lane l writes cols 2l,2l+1 (coalesced pairs)
    for (int i = 0; i < Msz; ++i) {
        const float ui = uf[i];                       // broadcast ds_read
        const float2 cmv = *(const float2*)(cm + (size_t)i * Msz + i0);
        float* orow = ob + (size_t)i * MA;
        orow[i0] = cmv.x + ui + lv0;
        orow[i1] = cmv.y + ui + lv1;
    }
    // col 128 for own rows
    ob[(size_t)i0 * MA + Msz] = alpha + lu0 + lc128;
    ob[(size_t)i1 * MA + Msz] = alpha + lu1 + lc128;
    // dustbin row 128: lane l writes cols 2l,2l+1; lane 0 writes corner
    float* odust = ob + (size_t)Msz * MA;
    odust[i0] = alpha + lr128 + lv0;
    odust[i1] = alpha + lr128 + lv1;
    if (l == 0) odust[Msz] = alpha + lr128 + lc128;
}

extern "C" void kernel_launch(void* const* d_in, const int* in_sizes, int n_in,
                              void* d_out, int out_size, void* d_ws, size_t ws_size,
                              hipStream_t stream) {
    const float* cost = (const float*)d_in[0];
    const float* bin  = (const float*)d_in[1];
    float* out        = (float*)d_out;
    sinkhorn_k<<<4, 64, 0, stream>>>(cost, bin, out);
}

// Round 7
// 29.615 us; speedup vs baseline: 270.9653x; 1.3944x over previous
//
#include <hip/hip_runtime.h>

typedef _Float16 half_t;
typedef _Float16 half2_t __attribute__((ext_vector_type(2)));

constexpr int Msz = 128;
constexpr int MA  = 129;
constexpr int ITERS_MAX = 800;      // safety cap; observed exit ~32-35 iters
constexpr float TOL = 5e-4f;        // rel-change stop tol

__device__ __forceinline__ float dot2(half2_t a, half2_t b, float acc) {
    return __builtin_amdgcn_fdot2(a, b, acc, false);
}
__device__ __forceinline__ half2_t u2h(unsigned int u) {
    union { unsigned int u; half2_t h; } c; c.u = u; return c.h;
}
__device__ __forceinline__ unsigned int pk2e(float a, float b) {
    union { half2_t h; unsigned int u; } c;
    c.h[0] = (half_t)__expf(a); c.h[1] = (half_t)__expf(b); return c.u;
}

#define FOR16(F) F(0) F(1) F(2) F(3) F(4) F(5) F(6) F(7) \
                 F(8) F(9) F(10) F(11) F(12) F(13) F(14) F(15)

// 2 waves per batch; lane l owns row l of K and column l of K.
// Per-lane K state = 32 named uint4 (128 regs) -> all-VGPR, no accvgpr
// traffic (round 6's 1-wave version needed 256 words -> half lived in AGPR
// with a v_accvgpr_read per dot2 operand, ~512 cyc/iter).
__global__ __launch_bounds__(128, 1) void sinkhorn_k(
    const float* __restrict__ cost,
    const float* __restrict__ bin,
    float* __restrict__ out)
{
    const int b = blockIdx.x;
    const int l = threadIdx.x;          // 0..127

    __shared__ alignas(16) unsigned int cb[64];   // c_{0..127} fp16
    __shared__ alignas(16) unsigned int rb[64];   // r_{0..127} fp16
    __shared__ alignas(8)  unsigned int flags[2]; // per-wave convergence vote
    __shared__ float uf[Msz];                     // log(r_i) for epilogue

    const float alpha = bin[0];
    const float ea    = __expf(alpha);
    const float* cm   = cost + (size_t)b * Msz * Msz;

#define DECLK(q) uint4 kr_##q, kt_##q;
    FOR16(DECLK)
#undef DECLK

    {
        const float4* r4 = (const float4*)(cm + (size_t)l * Msz);
#define INIT_KR(q) { \
        float4 x = r4[2*q], y = r4[2*q+1]; \
        kr_##q = make_uint4(pk2e(x.x,x.y), pk2e(x.z,x.w), pk2e(y.x,y.y), pk2e(y.z,y.w)); }
        FOR16(INIT_KR)
#undef INIT_KR
        // column l of K: coalesced across the 128 lanes at each row
#define INIT_KT(q) { \
        const float* p = cm + (size_t)(8*q) * Msz + l; \
        float a0=p[0], a1=p[128], a2=p[256], a3=p[384]; \
        float a4=p[512], a5=p[640], a6=p[768], a7=p[896]; \
        kt_##q = make_uint4(pk2e(a0,a1), pk2e(a2,a3), pk2e(a4,a5), pk2e(a6,a7)); }
        FOR16(INIT_KT)
#undef INIT_KT
    }

    const half2_t ONE = u2h(0x3C003C00u);   // {1,1} fp16

    ((half_t*)cb)[l] = (half_t)1.0f;        // c = 1 (v = 0)
    float c128 = 1.0f, r = 1.0f, r128 = 1.0f, cc = 1.0f;
    float pr = 0.f, pr128 = 0.f, pc = 0.f, pc128 = 0.f;
    __syncthreads();

    const uint4* cb4 = (const uint4*)cb;
    const uint4* rb4 = (const uint4*)rb;

    for (int it = 0; it < ITERS_MAX; ++it) {
        // ---------- u-phase: r = 1 / (K c)_l ; r128 = 128/(ea*sum(c)) ----------
        float sa = 0.f, sb = 0.f, sc = 0.f, sd = 0.f, ssA = 0.f, ssB = 0.f;
#define DOTU(q) { const uint4 cv = cb4[q]; \
        sa  = dot2(u2h(kr_##q.x), u2h(cv.x), sa); \
        ssA = dot2(ONE,           u2h(cv.x), ssA); \
        sb  = dot2(u2h(kr_##q.y), u2h(cv.y), sb); \
        ssB = dot2(ONE,           u2h(cv.y), ssB); \
        sc  = dot2(u2h(kr_##q.z), u2h(cv.z), sc); \
        ssA = dot2(ONE,           u2h(cv.z), ssA); \
        sd  = dot2(u2h(kr_##q.w), u2h(cv.w), sd); \
        ssB = dot2(ONE,           u2h(cv.w), ssB); }
        FOR16(DOTU)
#undef DOTU
        const float s    = ((sa + sb) + (sc + sd)) + ea * c128;
        const float sumc = (ssA + ssB) + c128;
        r    = __builtin_amdgcn_rcpf(s);
        r128 = 128.0f * __builtin_amdgcn_rcpf(ea * sumc);
        ((half_t*)rb)[l] = (half_t)r;
        const bool okU = (__builtin_fabsf(r - pr) <= TOL * pr) &&
                         (__builtin_fabsf(r128 - pr128) <= TOL * pr128);
        pr = r; pr128 = r128;
        __syncthreads();

        // ---------- v-phase: c = 1 / (K^T r)_l ; c128 = 128/(ea*sum(r)) ----------
        float ta = 0.f, tb = 0.f, tc = 0.f, td = 0.f, trA = 0.f, trB = 0.f;
#define DOTV(q) { const uint4 rv = rb4[q]; \
        ta  = dot2(u2h(kt_##q.x), u2h(rv.x), ta); \
        trA = dot2(ONE,           u2h(rv.x), trA); \
        tb  = dot2(u2h(kt_##q.y), u2h(rv.y), tb); \
        trB = dot2(ONE,           u2h(rv.y), trB); \
        tc  = dot2(u2h(kt_##q.z), u2h(rv.z), tc); \
        trA = dot2(ONE,           u2h(rv.z), trA); \
        td  = dot2(u2h(kt_##q.w), u2h(rv.w), td); \
        trB = dot2(ONE,           u2h(rv.w), trB); }
        FOR16(DOTV)
#undef DOTV
        const float t    = ((ta + tb) + (tc + td)) + ea * r128;
        const float sumr = (trA + trB) + r128;
        cc   = __builtin_amdgcn_rcpf(t);
        c128 = 128.0f * __builtin_amdgcn_rcpf(ea * sumr);
        ((half_t*)cb)[l] = (half_t)cc;
        const bool okV = (__builtin_fabsf(cc - pc) <= TOL * pc) &&
                         (__builtin_fabsf(c128 - pc128) <= TOL * pc128);
        pc = cc; pc128 = c128;
        const bool wall = __all(okU && okV);
        if ((l & 63) == 0) flags[l >> 6] = wall ? 1u : 0u;
        __syncthreads();
        // flags written before the barrier of iter t; next write is after the
        // u-phase barrier of iter t+1 -> no race with this read.
        if (it >= 16 && (flags[0] & flags[1])) break;
    }

    // ---------- output: Z = Z0 + log(r) + log(c), fully coalesced ----------
    const float lu = __logf(r), lv = __logf(cc);
    const float lr128 = __logf(r128), lc128 = __logf(c128);
    uf[l] = lu;
    __syncthreads();

    float* ob = out + (size_t)b * MA * MA;
    #pragma unroll 4
    for (int i = 0; i < Msz; ++i) {
        const float zi = cm[(size_t)i * Msz + l];   // coalesced
        ob[(size_t)i * MA + l] = zi + uf[i] + lv;   // coalesced
    }
    ob[(size_t)l * MA + Msz] = alpha + lu + lc128;  // own row's bin col
    float* odust = ob + (size_t)Msz * MA;
    odust[l] = alpha + lr128 + lv;                  // bin row
    if (l == 0) odust[Msz] = alpha + lr128 + lc128; // corner
}

extern "C" void kernel_launch(void* const* d_in, const int* in_sizes, int n_in,
                              void* d_out, int out_size, void* d_ws, size_t ws_size,
                              hipStream_t stream) {
    const float* cost = (const float*)d_in[0];
    const float* bin  = (const float*)d_in[1];
    float* out        = (float*)d_out;
    sinkhorn_k<<<4, 128, 0, stream>>>(cost, bin, out);
}

// Round 9
// 23.036 us; speedup vs baseline: 348.3571x; 1.2856x over previous
//
#include <hip/hip_runtime.h>

typedef _Float16 half_t;
typedef _Float16 half2_t __attribute__((ext_vector_type(2)));

constexpr int Msz = 128;
constexpr int MA  = 129;
constexpr int ITERS_MAX = 800;      // safety cap; expected exit ~12-18 iters
constexpr float TOL = 5e-4f;        // rel-change stop tol
constexpr float W   = 1.3f;         // over-relaxation factor (fixed point unchanged)
constexpr float W1  = 1.0f - W;
constexpr float LN2 = 0.69314718056f;

__device__ __forceinline__ float dot2(half2_t a, half2_t b, float acc) {
    return __builtin_amdgcn_fdot2(a, b, acc, false);
}
__device__ __forceinline__ half2_t u2h(unsigned int u) {
    union { unsigned int u; half2_t h; } c; c.u = u; return c.h;
}
__device__ __forceinline__ unsigned int pk2e(float a, float b) {
    union { half2_t h; unsigned int u; } c;
    c.h[0] = (half_t)__expf(a); c.h[1] = (half_t)__expf(b); return c.u;
}
// raw HW transcendentals: v_log_f32 is log2, v_exp_f32 is 2^x
__device__ __forceinline__ float hw_log2(float x) { return __builtin_amdgcn_logf(x); }
__device__ __forceinline__ float hw_exp2(float x) { return __builtin_amdgcn_exp2f(x); }

#define FOR16(F) F(0) F(1) F(2) F(3) F(4) F(5) F(6) F(7) \
                 F(8) F(9) F(10) F(11) F(12) F(13) F(14) F(15)

// 2 waves per batch; lane l owns row l and column l of K (all-VGPR).
// Over-relaxed Sinkhorn: r_new = r_sink^W * r_old^(1-W), done in log2 space
// on the per-lane scalars; fixed point identical to plain Sinkhorn.
__global__ __launch_bounds__(128, 1) void sinkhorn_k(
    const float* __restrict__ cost,
    const float* __restrict__ bin,
    float* __restrict__ out)
{
    const int b = blockIdx.x;
    const int l = threadIdx.x;          // 0..127

    __shared__ alignas(16) unsigned int cb[64];   // c_{0..127} fp16
    __shared__ alignas(16) unsigned int rb[64];   // r_{0..127} fp16
    __shared__ alignas(8)  unsigned int flags[2]; // per-wave convergence vote
    __shared__ float uf[Msz];                     // log(r_i) for epilogue

    const float alpha = bin[0];
    const float ea    = __expf(alpha);
    const float* cm   = cost + (size_t)b * Msz * Msz;

#define DECLK(q) uint4 kr_##q, kt_##q;
    FOR16(DECLK)
#undef DECLK

    {
        const float4* r4 = (const float4*)(cm + (size_t)l * Msz);
#define INIT_KR(q) { \
        float4 x = r4[2*q], y = r4[2*q+1]; \
        kr_##q = make_uint4(pk2e(x.x,x.y), pk2e(x.z,x.w), pk2e(y.x,y.y), pk2e(y.z,y.w)); }
        FOR16(INIT_KR)
#undef INIT_KR
#define INIT_KT(q) { \
        const float* p = cm + (size_t)(8*q) * Msz + l; \
        float a0=p[0], a1=p[128], a2=p[256], a3=p[384]; \
        float a4=p[512], a5=p[640], a6=p[768], a7=p[896]; \
        kt_##q = make_uint4(pk2e(a0,a1), pk2e(a2,a3), pk2e(a4,a5), pk2e(a6,a7)); }
        FOR16(INIT_KT)
#undef INIT_KT
    }

    const half2_t ONE = u2h(0x3C003C00u);   // {1,1} fp16

    ((half_t*)cb)[l] = (half_t)1.0f;        // c = 1 (v = 0)
    float c128 = 1.0f, r = 1.0f, r128 = 1.0f, cc = 1.0f;
    float lr = 0.f, lr128 = 0.f, lc = 0.f, lc128 = 0.f;   // log2 of current iterates
    float pr = 0.f, pr128 = 0.f, pc = 0.f, pc128 = 0.f;
    __syncthreads();

    const uint4* cb4 = (const uint4*)cb;
    const uint4* rb4 = (const uint4*)rb;

    for (int it = 0; it < ITERS_MAX; ++it) {
        // ---------- u-phase: r_sink = 1/(K c)_l ; over-relaxed blend ----------
        float sa = 0.f, sb = 0.f, sc = 0.f, sd = 0.f, ssA = 0.f, ssB = 0.f;
#define DOTU(q) { const uint4 cv = cb4[q]; \
        sa  = dot2(u2h(kr_##q.x), u2h(cv.x), sa); \
        ssA = dot2(ONE,           u2h(cv.x), ssA); \
        sb  = dot2(u2h(kr_##q.y), u2h(cv.y), sb); \
        ssB = dot2(ONE,           u2h(cv.y), ssB); \
        sc  = dot2(u2h(kr_##q.z), u2h(cv.z), sc); \
        ssA = dot2(ONE,           u2h(cv.z), ssA); \
        sd  = dot2(u2h(kr_##q.w), u2h(cv.w), sd); \
        ssB = dot2(ONE,           u2h(cv.w), ssB); }
        FOR16(DOTU)
#undef DOTU
        const float s    = ((sa + sb) + (sc + sd)) + ea * c128;
        const float sumc = (ssA + ssB) + c128;
        // blend in log2 space: lr_new = W*log2(r_sink) + (1-W)*lr_old
        lr    = W * hw_log2(__builtin_amdgcn_rcpf(s)) + W1 * lr;
        lr128 = W * hw_log2(128.0f * __builtin_amdgcn_rcpf(ea * sumc)) + W1 * lr128;
        r     = hw_exp2(lr);
        r128  = hw_exp2(lr128);
        ((half_t*)rb)[l] = (half_t)r;
        const bool okU = (__builtin_fabsf(r - pr) <= TOL * pr) &&
                         (__builtin_fabsf(r128 - pr128) <= TOL * pr128);
        pr = r; pr128 = r128;
        __syncthreads();

        // ---------- v-phase: c_sink = 1/(K^T r)_l ; over-relaxed blend ----------
        float ta = 0.f, tb = 0.f, tc = 0.f, td = 0.f, trA = 0.f, trB = 0.f;
#define DOTV(q) { const uint4 rv = rb4[q]; \
        ta  = dot2(u2h(kt_##q.x), u2h(rv.x), ta); \
        trA = dot2(ONE,           u2h(rv.x), trA); \
        tb  = dot2(u2h(kt_##q.y), u2h(rv.y), tb); \
        trB = dot2(ONE,           u2h(rv.y), trB); \
        tc  = dot2(u2h(kt_##q.z), u2h(rv.z), tc); \
        trA = dot2(ONE,           u2h(rv.z), trA); \
        td  = dot2(u2h(kt_##q.w), u2h(rv.w), td); \
        trB = dot2(ONE,           u2h(rv.w), trB); }
        FOR16(DOTV)
#undef DOTV
        const float t    = ((ta + tb) + (tc + td)) + ea * r128;
        const float sumr = (trA + trB) + r128;
        lc    = W * hw_log2(__builtin_amdgcn_rcpf(t)) + W1 * lc;
        lc128 = W * hw_log2(128.0f * __builtin_amdgcn_rcpf(ea * sumr)) + W1 * lc128;
        cc    = hw_exp2(lc);
        c128  = hw_exp2(lc128);
        ((half_t*)cb)[l] = (half_t)cc;
        const bool okV = (__builtin_fabsf(cc - pc) <= TOL * pc) &&
                         (__builtin_fabsf(c128 - pc128) <= TOL * pc128);
        pc = cc; pc128 = c128;
        const bool wall = __all(okU && okV);
        if ((l & 63) == 0) flags[l >> 6] = wall ? 1u : 0u;
        __syncthreads();
        if (it >= 6 && (flags[0] & flags[1])) break;
    }

    // ---------- output: Z = Z0 + log(r) + log(c), fully coalesced ----------
    const float lu = lr * LN2, lv = lc * LN2;
    const float lnr128 = lr128 * LN2, lnc128 = lc128 * LN2;
    uf[l] = lu;
    __syncthreads();

    float* ob = out + (size_t)b * MA * MA;
    #pragma unroll 4
    for (int i = 0; i < Msz; ++i) {
        const float zi = cm[(size_t)i * Msz + l];   // coalesced
        ob[(size_t)i * MA + l] = zi + uf[i] + lv;   // coalesced
    }
    ob[(size_t)l * MA + Msz] = alpha + lu + lnc128; // own row's bin col
    float* odust = ob + (size_t)Msz * MA;
    odust[l] = alpha + lnr128 + lv;                 // bin row
    if (l == 0) odust[Msz] = alpha + lnr128 + lnc128; // corner
}

extern "C" void kernel_launch(void* const* d_in, const int* in_sizes, int n_in,
                              void* d_out, int out_size, void* d_ws, size_t ws_size,
                              hipStream_t stream) {
    const float* cost = (const float*)d_in[0];
    const float* bin  = (const float*)d_in[1];
    float* out        = (float*)d_out;
    sinkhorn_k<<<4, 128, 0, stream>>>(cost, bin, out);
}

// Round 10
// 20.755 us; speedup vs baseline: 386.6374x; 1.1099x over previous
//
#include <hip/hip_runtime.h>

typedef _Float16 half_t;
typedef _Float16 half2_t __attribute__((ext_vector_type(2)));

constexpr int Msz = 128;
constexpr int MA  = 129;
constexpr int ITERS_MAX = 800;      // safety cap; expected exit ~10-13 iters
constexpr float TOL = 2e-3f;        // rel-change stop tol (fp16 jitter ~5e-4)
constexpr float W   = 1.3f;         // over-relaxation factor (fixed point unchanged)
constexpr float W1  = 1.0f - W;
constexpr float LN2 = 0.69314718056f;

__device__ __forceinline__ float dot2(half2_t a, half2_t b, float acc) {
    return __builtin_amdgcn_fdot2(a, b, acc, false);
}
__device__ __forceinline__ half2_t u2h(unsigned int u) {
    union { unsigned int u; half2_t h; } c; c.u = u; return c.h;
}
__device__ __forceinline__ unsigned int pk2e(float a, float b) {
    union { half2_t h; unsigned int u; } c;
    c.h[0] = (half_t)__expf(a); c.h[1] = (half_t)__expf(b); return c.u;
}
__device__ __forceinline__ unsigned int packh(half_t a, half_t b) {
    union { half2_t h; unsigned int u; } c; c.h[0] = a; c.h[1] = b; return c.u;
}
// raw HW transcendentals: v_log_f32 is log2, v_exp_f32 is 2^x
__device__ __forceinline__ float hw_log2(float x) { return __builtin_amdgcn_logf(x); }
__device__ __forceinline__ float hw_exp2(float x) { return __builtin_amdgcn_exp2f(x); }

#define FOR16(F) F(0) F(1) F(2) F(3) F(4) F(5) F(6) F(7) \
                 F(8) F(9) F(10) F(11) F(12) F(13) F(14) F(15)

// 2 waves per batch; lane l owns row l and column l of K (all-VGPR).
// Init: exp(row) computed once per element, shared through a padded LDS tile
// (vector writes, free 2-way-conflict scalar column reads) — no global column
// re-reads, half the expf count of rounds 7-9.
__global__ __launch_bounds__(128, 1) void sinkhorn_k(
    const float* __restrict__ cost,
    const float* __restrict__ bin,
    float* __restrict__ out)
{
    const int b = blockIdx.x;
    const int l = threadIdx.x;          // 0..127

    __shared__ half_t Ksh[128][136];              // K tile, +8 hal//row pad
    __shared__ alignas(16) unsigned int cb[64];   // c_{0..127} fp16
    __shared__ alignas(16) unsigned int rb[64];   // r_{0..127} fp16
    __shared__ alignas(8)  unsigned int flags[2]; // per-wave convergence vote
    __shared__ float uf[Msz];                     // log(r_i) for epilogue

    const float alpha = bin[0];
    const float ea    = __expf(alpha);
    const float* cm   = cost + (size_t)b * Msz * Msz;

#define DECLK(q) uint4 kr_##q, kt_##q;
    FOR16(DECLK)
#undef DECLK

    {
        const float4* r4 = (const float4*)(cm + (size_t)l * Msz);
        half_t* row = &Ksh[l][0];                  // l*272B: 16B-aligned
#define INIT_KR(q) { \
        float4 x = r4[2*q], y = r4[2*q+1]; \
        kr_##q = make_uint4(pk2e(x.x,x.y), pk2e(x.z,x.w), pk2e(y.x,y.y), pk2e(y.z,y.w)); \
        *(uint4*)(row + 8*q) = kr_##q; }
        FOR16(INIT_KR)
#undef INIT_KR
    }
    ((half_t*)cb)[l] = (half_t)1.0f;               // c = 1 (v = 0)
    __syncthreads();
    {
#define INIT_KT(q) { \
        kt_##q = make_uint4(packh(Ksh[8*q+0][l], Ksh[8*q+1][l]), \
                            packh(Ksh[8*q+2][l], Ksh[8*q+3][l]), \
                            packh(Ksh[8*q+4][l], Ksh[8*q+5][l]), \
                            packh(Ksh[8*q+6][l], Ksh[8*q+7][l])); }
        FOR16(INIT_KT)
#undef INIT_KT
    }

    const half2_t ONE = u2h(0x3C003C00u);   // {1,1} fp16

    float c128 = 1.0f, r = 1.0f, r128 = 1.0f, cc = 1.0f;
    float lr = 0.f, lr128 = 0.f, lc = 0.f, lc128 = 0.f;   // log2 of iterates
    float pr = 0.f, pr128 = 0.f, pc = 0.f, pc128 = 0.f;

    const uint4* cb4 = (const uint4*)cb;
    const uint4* rb4 = (const uint4*)rb;

    for (int it = 0; it < ITERS_MAX; ++it) {
        // ---------- u-phase: r_sink = 1/(K c)_l ; over-relaxed blend ----------
        float sa = 0.f, sb = 0.f, sc = 0.f, sd = 0.f, ssA = 0.f, ssB = 0.f;
#define DOTU(q) { const uint4 cv = cb4[q]; \
        sa  = dot2(u2h(kr_##q.x), u2h(cv.x), sa); \
        ssA = dot2(ONE,           u2h(cv.x), ssA); \
        sb  = dot2(u2h(kr_##q.y), u2h(cv.y), sb); \
        ssB = dot2(ONE,           u2h(cv.y), ssB); \
        sc  = dot2(u2h(kr_##q.z), u2h(cv.z), sc); \
        ssA = dot2(ONE,           u2h(cv.z), ssA); \
        sd  = dot2(u2h(kr_##q.w), u2h(cv.w), sd); \
        ssB = dot2(ONE,           u2h(cv.w), ssB); }
        FOR16(DOTU)
#undef DOTU
        const float s    = ((sa + sb) + (sc + sd)) + ea * c128;
        const float sumc = (ssA + ssB) + c128;
        lr    = W * hw_log2(__builtin_amdgcn_rcpf(s)) + W1 * lr;
        lr128 = W * hw_log2(128.0f * __builtin_amdgcn_rcpf(ea * sumc)) + W1 * lr128;
        r     = hw_exp2(lr);
        r128  = hw_exp2(lr128);
        ((half_t*)rb)[l] = (half_t)r;
        const bool okU = (__builtin_fabsf(r - pr) <= TOL * pr) &&
                         (__builtin_fabsf(r128 - pr128) <= TOL * pr128);
        pr = r; pr128 = r128;
        __syncthreads();

        // ---------- v-phase: c_sink = 1/(K^T r)_l ; over-relaxed blend ----------
        float ta = 0.f, tb = 0.f, tc = 0.f, td = 0.f, trA = 0.f, trB = 0.f;
#define DOTV(q) { const uint4 rv = rb4[q]; \
        ta  = dot2(u2h(kt_##q.x), u2h(rv.x), ta); \
        trA = dot2(ONE,           u2h(rv.x), trA); \
        tb  = dot2(u2h(kt_##q.y), u2h(rv.y), tb); \
        trB = dot2(ONE,           u2h(rv.y), trB); \
        tc  = dot2(u2h(kt_##q.z), u2h(rv.z), tc); \
        trA = dot2(ONE,           u2h(rv.z), trA); \
        td  = dot2(u2h(kt_##q.w), u2h(rv.w), td); \
        trB = dot2(ONE,           u2h(rv.w), trB); }
        FOR16(DOTV)
#undef DOTV
        const float t    = ((ta + tb) + (tc + td)) + ea * r128;
        const float sumr = (trA + trB) + r128;
        lc    = W * hw_log2(__builtin_amdgcn_rcpf(t)) + W1 * lc;
        lc128 = W * hw_log2(128.0f * __builtin_amdgcn_rcpf(ea * sumr)) + W1 * lc128;
        cc    = hw_exp2(lc);
        c128  = hw_exp2(lc128);
        ((half_t*)cb)[l] = (half_t)cc;
        const bool okV = (__builtin_fabsf(cc - pc) <= TOL * pc) &&
                         (__builtin_fabsf(c128 - pc128) <= TOL * pc128);
        pc = cc; pc128 = c128;
        const bool wall = __all(okU && okV);
        if ((l & 63) == 0) flags[l >> 6] = wall ? 1u : 0u;
        __syncthreads();
        if (it >= 4 && (flags[0] & flags[1])) break;
    }

    // ---------- output: Z = Z0 + log(r) + log(c), fully coalesced ----------
    const float lu = lr * LN2, lv = lc * LN2;
    const float lnr128 = lr128 * LN2, lnc128 = lc128 * LN2;
    uf[l] = lu;
    __syncthreads();

    float* ob = out + (size_t)b * MA * MA;
    #pragma unroll 4
    for (int i = 0; i < Msz; ++i) {
        const float zi = cm[(size_t)i * Msz + l];   // coalesced
        ob[(size_t)i * MA + l] = zi + uf[i] + lv;   // coalesced
    }
    ob[(size_t)l * MA + Msz] = alpha + lu + lnc128; // own row's bin col
    float* odust = ob + (size_t)Msz * MA;
    odust[l] = alpha + lnr128 + lv;                 // bin row
    if (l == 0) odust[Msz] = alpha + lnr128 + lnc128; // corner
}

extern "C" void kernel_launch(void* const* d_in, const int* in_sizes, int n_in,
                              void* d_out, int out_size, void* d_ws, size_t ws_size,
                              hipStream_t stream) {
    const float* cost = (const float*)d_in[0];
    const float* bin  = (const float*)d_in[1];
    float* out        = (float*)d_out;
    sinkhorn_k<<<4, 128, 0, stream>>>(cost, bin, out);
}